// Round 7
// baseline (190.636 us; speedup 1.0000x reference)
//
#include <hip/hip_runtime.h>
#include <hip/hip_bf16.h>

// DepthLossWithMask: loss = sum(|output - label0| * label1) / count(label0 != 0)
// N = 16*15*256*256 = 15,728,640 floats -> n4 = 3,932,160 float4 = 7.5 * 524288.
//
// R1-R6: compiler collapsed every source-level load pipeline (VGPR 52/28/20/32),
// stage1 pinned at ~67-75us (~2.8 TB/s effective). R7: inline-asm
// global_load_dwordx4 with hand-placed s_waitcnt vmcnt(N) — 12 dwordx4
// genuinely outstanding per wave (4 rotating buffer sets, prefetch distance 3).
// Registers pinned by asm constraints; waitcnt asm takes buffers "+v" so the
// consume is data-dependent on the wait. If this still lands ~67us, the ~3 TB/s
// plateau is the machine ceiling (harness D2D restore also runs ~3.2 TB/s).

#define THREADS 256
#define BLOCKS  2048
#define SSTRIDE (BLOCKS * THREADS)   // 524288 float4 per sweep
#define ITERS   8                    // n4 = 7.5 * SSTRIDE; iter 7 half-populated

typedef float f32x4 __attribute__((ext_vector_type(4)));

struct Partial {
    float s;
    unsigned int c;
};

__device__ __forceinline__ f32x4 gload(const f32x4* p) {
    f32x4 r;
    asm volatile("global_load_dwordx4 %0, %1, off" : "=v"(r) : "v"(p));
    return r;
}

// s_waitcnt vmcnt(N), with the iteration's 3 buffers passed through so the
// consumer reads post-wait values (data dependence on the wait, not the load).
#define WAITP(N, x, y, z) \
    asm volatile("s_waitcnt vmcnt(" #N ")" : "+v"(x), "+v"(y), "+v"(z) :: "memory")

__device__ __forceinline__ void accum(const f32x4& o, const f32x4& a,
                                      const f32x4& w, float& sum,
                                      unsigned int& cnt) {
    sum += fabsf(o.x - a.x) * w.x;
    sum += fabsf(o.y - a.y) * w.y;
    sum += fabsf(o.z - a.z) * w.z;
    sum += fabsf(o.w - a.w) * w.w;
    cnt += (a.x != 0.0f) + (a.y != 0.0f) + (a.z != 0.0f) + (a.w != 0.0f);
}

__global__ __launch_bounds__(THREADS, 6)
void depth_loss_stage1(const f32x4* __restrict__ out,
                       const f32x4* __restrict__ l0,
                       const f32x4* __restrict__ l1,
                       Partial* __restrict__ partials,
                       int n4) {
    const int tid = blockIdx.x * THREADS + threadIdx.x;
    const int tail_n = n4 - (ITERS - 1) * SSTRIDE;   // 262144

    f32x4 o[4], a[4], w[4];

    // Prologue: issue iterations 0..2 (9 loads outstanding).
    #pragma unroll
    for (int k = 0; k < 3; ++k) {
        const int j = tid + k * SSTRIDE;
        o[k] = gload(out + j);
        a[k] = gload(l0 + j);
        w[k] = gload(l1 + j);
    }

    float sum = 0.0f;
    unsigned int cnt = 0;

    #pragma unroll
    for (int k = 0; k < ITERS; ++k) {
        const int kp = k + 3;
        if (kp < ITERS) {                 // constant-folded per unrolled k
            int j = tid + kp * SSTRIDE;
            if (kp == ITERS - 1) j = (tid < tail_n) ? j : tid;  // clamp tail
            const int s = kp & 3;
            o[s] = gload(out + j);
            a[s] = gload(l0 + j);
            w[s] = gload(l1 + j);
        }
        const int s = k & 3;
        // Outstanding after issue: 12 (k<=4), 9 (k=5), 6 (k=6), 3 (k=7).
        // Wait until iteration k's 3 loads (the oldest) have retired.
        if      (k <= 4) { WAITP(9, o[s], a[s], w[s]); }
        else if (k == 5) { WAITP(6, o[s], a[s], w[s]); }
        else if (k == 6) { WAITP(3, o[s], a[s], w[s]); }
        else             { WAITP(0, o[s], a[s], w[s]); }

        if (k < ITERS - 1 || tid < tail_n) {
            accum(o[s], a[s], w[s], sum, cnt);
        }
    }

    // wave-64 butterfly reduce
    #pragma unroll
    for (int off = 32; off > 0; off >>= 1) {
        sum += __shfl_down(sum, off, 64);
        cnt += __shfl_down(cnt, off, 64);
    }

    __shared__ float        sv[THREADS / 64];
    __shared__ unsigned int sc[THREADS / 64];
    int lane = threadIdx.x & 63;
    int wid  = threadIdx.x >> 6;
    if (lane == 0) { sv[wid] = sum; sc[wid] = cnt; }
    __syncthreads();

    if (threadIdx.x == 0) {
        float bs = 0.0f;
        unsigned int bc = 0;
        #pragma unroll
        for (int k = 0; k < THREADS / 64; ++k) { bs += sv[k]; bc += sc[k]; }
        Partial p; p.s = bs; p.c = bc;
        partials[blockIdx.x] = p;   // plain 8B store, no contention
    }
}

__global__ __launch_bounds__(THREADS)
void depth_loss_stage2(const Partial* __restrict__ partials,
                       int nblocks,
                       float* __restrict__ out) {
    double sum = 0.0;
    unsigned int cnt = 0;
    for (int i = threadIdx.x; i < nblocks; i += THREADS) {
        Partial p = partials[i];
        sum += (double)p.s;
        cnt += p.c;
    }

    #pragma unroll
    for (int off = 32; off > 0; off >>= 1) {
        sum += __shfl_down(sum, off, 64);
        cnt += __shfl_down(cnt, off, 64);
    }

    __shared__ double       sv[THREADS / 64];
    __shared__ unsigned int sc[THREADS / 64];
    int lane = threadIdx.x & 63;
    int wid  = threadIdx.x >> 6;
    if (lane == 0) { sv[wid] = sum; sc[wid] = cnt; }
    __syncthreads();

    if (threadIdx.x == 0) {
        double bs = 0.0;
        unsigned int bc = 0;
        #pragma unroll
        for (int k = 0; k < THREADS / 64; ++k) { bs += sv[k]; bc += sc[k]; }
        out[0] = (bc == 0) ? 0.0f : (float)(bs / (double)bc);
    }
}

extern "C" void kernel_launch(void* const* d_in, const int* in_sizes, int n_in,
                              void* d_out, int out_size, void* d_ws, size_t ws_size,
                              hipStream_t stream) {
    const float* output = (const float*)d_in[0];
    const float* label0 = (const float*)d_in[1];
    const float* label1 = (const float*)d_in[2];
    int n = in_sizes[0];           // 15,728,640
    int n4 = n >> 2;               // 3,932,160 float4

    Partial* partials = (Partial*)d_ws;   // 2048*8 = 16 KB, every slot written

    depth_loss_stage1<<<BLOCKS, THREADS, 0, stream>>>(
        (const f32x4*)output, (const f32x4*)label0, (const f32x4*)label1,
        partials, n4);

    depth_loss_stage2<<<1, THREADS, 0, stream>>>(
        partials, BLOCKS, (float*)d_out);
}

// Round 8
// 188.076 us; speedup vs baseline: 1.0136x; 1.0136x over previous
//
#include <hip/hip_runtime.h>
#include <hip/hip_bf16.h>

// DepthLossWithMask: loss = sum(|output - label0| * label1) / count(label0 != 0)
// N = 16*15*256*256 = 15,728,640 floats -> n4 = 3,932,160 float4.
//
// FINAL (R3 variant, best on record: total 187.2us, stage1 67.0us).
// Roofline evidence (R1-R7): HBM delivery pinned at 1.37-1.40 TB/s across
// four structurally independent kernel shapes (one-shot atomics, two-stage,
// persistent pipelined, inline-asm vmcnt pipeline); harness's own D2D restore
// runs the same ~1.6 TB/s/direction. stage1 time == FETCH_SIZE / hbm_rate
// (92MB / 1.37 TB/s = 67us): exactly HBM-fetch-bound on this platform slice.
// Data volume (188.7MB, each array read once, fp32-exact) is irreducible.

#define REDUCE_THREADS 256
#define EPT 8   // float4 chunks per thread; block covers 256*8 = 2048 float4

struct Partial {
    float s;
    unsigned int c;
};

__global__ __launch_bounds__(REDUCE_THREADS)
void depth_loss_stage1(const float4* __restrict__ out,
                       const float4* __restrict__ l0,
                       const float4* __restrict__ l1,
                       Partial* __restrict__ partials,
                       int n4) {
    const int base = blockIdx.x * (REDUCE_THREADS * EPT) + threadIdx.x;

    float4 o[EPT], a[EPT], w[EPT];
    #pragma unroll
    for (int k = 0; k < EPT; ++k) {
        int i = base + k * REDUCE_THREADS;
        bool ok = (i < n4);
        int j = ok ? i : 0;
        o[k] = out[j];
        a[k] = l0[j];
        w[k] = l1[j];
        if (!ok) {
            a[k] = make_float4(0.f, 0.f, 0.f, 0.f);
            o[k] = make_float4(0.f, 0.f, 0.f, 0.f);
            w[k] = make_float4(0.f, 0.f, 0.f, 0.f);
        }
    }

    float sum = 0.0f;
    unsigned int cnt = 0;
    #pragma unroll
    for (int k = 0; k < EPT; ++k) {
        sum += fabsf(o[k].x - a[k].x) * w[k].x;
        sum += fabsf(o[k].y - a[k].y) * w[k].y;
        sum += fabsf(o[k].z - a[k].z) * w[k].z;
        sum += fabsf(o[k].w - a[k].w) * w[k].w;
        cnt += (a[k].x != 0.0f) + (a[k].y != 0.0f) +
               (a[k].z != 0.0f) + (a[k].w != 0.0f);
    }

    // wave-64 butterfly reduce
    #pragma unroll
    for (int off = 32; off > 0; off >>= 1) {
        sum += __shfl_down(sum, off, 64);
        cnt += __shfl_down(cnt, off, 64);
    }

    __shared__ float        sv[REDUCE_THREADS / 64];
    __shared__ unsigned int sc[REDUCE_THREADS / 64];
    int lane = threadIdx.x & 63;
    int wid  = threadIdx.x >> 6;
    if (lane == 0) { sv[wid] = sum; sc[wid] = cnt; }
    __syncthreads();

    if (threadIdx.x == 0) {
        float bs = 0.0f;
        unsigned int bc = 0;
        #pragma unroll
        for (int i = 0; i < REDUCE_THREADS / 64; ++i) { bs += sv[i]; bc += sc[i]; }
        Partial p; p.s = bs; p.c = bc;
        partials[blockIdx.x] = p;   // plain 8B store, no contention
    }
}

__global__ __launch_bounds__(REDUCE_THREADS)
void depth_loss_stage2(const Partial* __restrict__ partials,
                       int nblocks,
                       float* __restrict__ out) {
    double sum = 0.0;
    unsigned int cnt = 0;
    for (int i = threadIdx.x; i < nblocks; i += REDUCE_THREADS) {
        Partial p = partials[i];
        sum += (double)p.s;
        cnt += p.c;
    }

    #pragma unroll
    for (int off = 32; off > 0; off >>= 1) {
        sum += __shfl_down(sum, off, 64);
        cnt += __shfl_down(cnt, off, 64);
    }

    __shared__ double       sv[REDUCE_THREADS / 64];
    __shared__ unsigned int sc[REDUCE_THREADS / 64];
    int lane = threadIdx.x & 63;
    int wid  = threadIdx.x >> 6;
    if (lane == 0) { sv[wid] = sum; sc[wid] = cnt; }
    __syncthreads();

    if (threadIdx.x == 0) {
        double bs = 0.0;
        unsigned int bc = 0;
        #pragma unroll
        for (int i = 0; i < REDUCE_THREADS / 64; ++i) { bs += sv[i]; bc += sc[i]; }
        out[0] = (bc == 0) ? 0.0f : (float)(bs / (double)bc);
    }
}

extern "C" void kernel_launch(void* const* d_in, const int* in_sizes, int n_in,
                              void* d_out, int out_size, void* d_ws, size_t ws_size,
                              hipStream_t stream) {
    const float* output = (const float*)d_in[0];
    const float* label0 = (const float*)d_in[1];
    const float* label1 = (const float*)d_in[2];
    int n = in_sizes[0];           // 15,728,640
    int n4 = n >> 2;               // 3,932,160 float4

    int per_block = REDUCE_THREADS * EPT;           // 2048 float4 per block
    int blocks = (n4 + per_block - 1) / per_block;  // 1920

    Partial* partials = (Partial*)d_ws;             // 1920*8 = 15 KB, all written

    depth_loss_stage1<<<blocks, REDUCE_THREADS, 0, stream>>>(
        (const float4*)output, (const float4*)label0, (const float4*)label1,
        partials, n4);

    depth_loss_stage2<<<1, REDUCE_THREADS, 0, stream>>>(
        partials, blocks, (float*)d_out);
}